// Round 7
// baseline (353.635 us; speedup 1.0000x reference)
//
#include <hip/hip_runtime.h>

#define HSZ 32
#define SEQ 1024

typedef float v2f __attribute__((ext_vector_type(2)));

__device__ __forceinline__ float fast_rcp(float v) { return __builtin_amdgcn_rcpf(v); }

// sigmoid(x) = 1/(1+exp(-x)); exp args bounded (|g| <~ 10), rcp(inf)=0 saturation safe.
__device__ __forceinline__ float sigmoidf_(float v) {
    return fast_rcp(1.0f + __expf(-v));
}
__device__ __forceinline__ float tanhf_(float v) {
    return fmaf(2.0f, sigmoidf_(2.0f * v), -1.0f);
}

__device__ __forceinline__ float swz_add(float v, const int imm) {
    return v; // placeholder (specialized below)
}

// One wave per block, TWO batch elements per wave (one per 32-lane half).
// Lane u of a half owns rows u,u+32,u+64,u+96 = all four gates of unit u.
// Single-wave blocks + half-private LDS regions -> NO barriers needed anywhere:
// the DS pipe is in-order per wave, lgkmcnt waits give RAW correctness.
// waves_per_eu(2,2): proven-honored 256-VGPR budget (r4); working set ~225.
__global__ __launch_bounds__(64)
__attribute__((amdgpu_waves_per_eu(2, 2)))
void lstm_attn_fused(const float* __restrict__ x,
                     const float* __restrict__ W_ih,
                     const float* __restrict__ W_hh,
                     const float* __restrict__ b_ih,
                     const float* __restrict__ b_hh,
                     const float* __restrict__ attn_w,
                     const float* __restrict__ fc1_w,
                     const float* __restrict__ fc1_b,
                     const float* __restrict__ fc2_w,
                     const float* __restrict__ fc2_b,
                     float* __restrict__ out)
{
    const int lane = threadIdx.x;        // 0..63
    const int half = lane >> 5;          // which batch element of this block
    const int u    = lane & 31;          // hidden unit owned by this lane
    const int bsel = blockIdx.x * 2 + half;

    // ---- preload weights: 4 gate rows per lane, v2 packed for v_pk_fma_f32 ----
    const v2f* __restrict__ Whv = (const v2f*)W_hh;      // [128][16] v2f
    v2f wI[16], wF[16], wG[16], wO[16];
#pragma unroll
    for (int k = 0; k < 16; ++k) {
        wI[k] = Whv[(u      ) * 16 + k];
        wF[k] = Whv[(u + 32 ) * 16 + k];
        wG[k] = Whv[(u + 64 ) * 16 + k];
        wO[k] = Whv[(u + 96 ) * 16 + k];
    }
    float wiI[3], wiF[3], wiG[3], wiO[3];
#pragma unroll
    for (int j = 0; j < 3; ++j) {
        wiI[j] = W_ih[(u      ) * 3 + j];
        wiF[j] = W_ih[(u + 32 ) * 3 + j];
        wiG[j] = W_ih[(u + 64 ) * 3 + j];
        wiO[j] = W_ih[(u + 96 ) * 3 + j];
    }
    float bI = b_ih[u     ] + b_hh[u     ];
    float bF = b_ih[u + 32] + b_hh[u + 32];
    float bG = b_ih[u + 64] + b_hh[u + 64];
    float bO = b_ih[u + 96] + b_hh[u + 96];
    float aw = attn_w[u];                // this lane's attention weight

    // Pin loop-invariants (asm defs can't be rematerialized from memory).
#pragma unroll
    for (int k = 0; k < 16; ++k) {
        asm volatile("" : "+v"(wI[k]), "+v"(wF[k]), "+v"(wG[k]), "+v"(wO[k]));
    }
#pragma unroll
    for (int j = 0; j < 3; ++j) {
        asm volatile("" : "+v"(wiI[j]), "+v"(wiF[j]), "+v"(wiG[j]), "+v"(wiO[j]));
    }
    asm volatile("" : "+v"(bI), "+v"(bF), "+v"(bG), "+v"(bO), "+v"(aw));

    // h state: [0..31]=half0, [32..63]=half1. Intra-wave use only -> no barriers.
    __shared__ float hbuf[64];
    hbuf[lane] = 0.0f;

    float c = 0.0f, h = 0.0f;
    float Pacc = 0.0f, lacc = 0.0f;      // online softmax pooling (scores bounded ~5.7)

    const float4* __restrict__ xv = (const float4*)(x + (size_t)bsel * SEQ * 3);
    const v2f* __restrict__ hb2 = (const v2f*)hbuf + (half << 4);

    auto step = [&](float x0, float x1, float x2) {
        // read previous h (8x ds_read_b128 after compiler merge)
        v2f hp[16];
#pragma unroll
        for (int k = 0; k < 16; ++k) hp[k] = hb2[k];

        v2f aI; aI.x = fmaf(wiI[0],x0, fmaf(wiI[1],x1, fmaf(wiI[2],x2, bI))); aI.y = 0.0f;
        v2f aF; aF.x = fmaf(wiF[0],x0, fmaf(wiF[1],x1, fmaf(wiF[2],x2, bF))); aF.y = 0.0f;
        v2f aG; aG.x = fmaf(wiG[0],x0, fmaf(wiG[1],x1, fmaf(wiG[2],x2, bG))); aG.y = 0.0f;
        v2f aO; aO.x = fmaf(wiO[0],x0, fmaf(wiO[1],x1, fmaf(wiO[2],x2, bO))); aO.y = 0.0f;
#pragma unroll
        for (int k = 0; k < 16; ++k) {
            aI = __builtin_elementwise_fma(wI[k], hp[k], aI);
            aF = __builtin_elementwise_fma(wF[k], hp[k], aF);
            aG = __builtin_elementwise_fma(wG[k], hp[k], aG);
            aO = __builtin_elementwise_fma(wO[k], hp[k], aO);
        }

        // gates -- all lane-local
        const float i_ = sigmoidf_(aI.x + aI.y);
        const float f_ = sigmoidf_(aF.x + aF.y);
        const float gg = tanhf_   (aG.x + aG.y);
        const float o_ = sigmoidf_(aO.x + aO.y);

        c = fmaf(f_, c, i_ * gg);
        h = o_ * tanhf_(c);

        hbuf[lane] = h;                  // next step's ds_reads ordered after this (DS in-order)

        // attention score of THIS h: p = sum_u h[u]*aw[u] over the half (off the h-chain)
        float p = h * aw;
        p += __int_as_float(__builtin_amdgcn_ds_swizzle(__float_as_int(p), 0x041F)); // xor 1
        p += __int_as_float(__builtin_amdgcn_ds_swizzle(__float_as_int(p), 0x081F)); // xor 2
        p += __int_as_float(__builtin_amdgcn_ds_swizzle(__float_as_int(p), 0x101F)); // xor 4
        p += __int_as_float(__builtin_amdgcn_ds_swizzle(__float_as_int(p), 0x201F)); // xor 8
        p += __int_as_float(__builtin_amdgcn_ds_swizzle(__float_as_int(p), 0x401F)); // xor 16
        const float wgt = __expf(fmaxf(p, 0.0f));
        lacc += wgt;
        Pacc = fmaf(wgt, h, Pacc);
    };

    // x software pipeline: prefetch next 4-step group while computing current
    float4 xa = xv[0], xb = xv[1], xc = xv[2];
    for (int s0 = 0; s0 < SEQ; s0 += 4) {
        const int nfi = ((s0 + 4) < SEQ) ? (((s0 + 4) * 3) >> 2) : 0;
        const float4 na = xv[nfi], nb = xv[nfi + 1], nc = xv[nfi + 2];
        step(xa.x, xa.y, xa.z);
        step(xa.w, xb.x, xb.y);
        step(xb.z, xb.w, xc.x);
        step(xc.y, xc.z, xc.w);
        xa = na; xb = nb; xc = nc;
    }

    // ---- epilogue: pooled -> fc1(relu) -> fc2, per half (still single-wave, no barriers) ----
    hbuf[lane] = Pacc * fast_rcp(lacc);  // pooled[u] of this half's batch

    {
        const int j = lane & 15;         // fc1 row (lanes 16..31 redundant)
        const float* __restrict__ hb = hbuf + (half << 5);
        float acc = fc1_b[j];
#pragma unroll
        for (int k = 0; k < HSZ; ++k)
            acc = fmaf(fc1_w[j * HSZ + k], hb[k], acc);
        __shared__ float h1sh[2][16];
        if ((lane & 31) < 16) h1sh[half][j] = fmaxf(acc, 0.0f);

        if ((lane & 31) < 2) {
            const int oi = lane & 31;
            float acc2 = fc2_b[oi];
#pragma unroll
            for (int m = 0; m < 16; ++m)
                acc2 = fmaf(fc2_w[oi * 16 + m], h1sh[half][m], acc2);
            out[bsel * 2 + oi] = acc2;
        }
    }
}

extern "C" void kernel_launch(void* const* d_in, const int* in_sizes, int n_in,
                              void* d_out, int out_size, void* d_ws, size_t ws_size,
                              hipStream_t stream) {
    const float* x      = (const float*)d_in[0];
    const float* W_ih   = (const float*)d_in[1];
    const float* W_hh   = (const float*)d_in[2];
    const float* b_ih   = (const float*)d_in[3];
    const float* b_hh   = (const float*)d_in[4];
    const float* attn_w = (const float*)d_in[5];
    const float* fc1_w  = (const float*)d_in[6];
    const float* fc1_b  = (const float*)d_in[7];
    const float* fc2_w  = (const float*)d_in[8];
    const float* fc2_b  = (const float*)d_in[9];

    const int B = in_sizes[0] / (SEQ * 3);   // 2048

    lstm_attn_fused<<<dim3(B / 2), dim3(64), 0, stream>>>(
        x, W_ih, W_hh, b_ih, b_hh, attn_w, fc1_w, fc1_b, fc2_w, fc2_b,
        (float*)d_out);
}